// Round 2
// baseline (257.083 us; speedup 1.0000x reference)
//
#include <hip/hip_runtime.h>
#include <math.h>

#define T_TOTAL 16384
#define HDIM    2048
#define NEXP    64
#define KS_MAIN 4

typedef unsigned short ushort_t;
using bf16x8 = __attribute__((ext_vector_type(8))) short;
using f32x4  = __attribute__((ext_vector_type(4))) float;

// ---------------------------------------------------------------------------
// fp32 -> bf16 split helpers. x = hi + mid + lo exactly to O(2^-27 |x|):
// residuals (x - hi), (r1 - mid) are exactly representable in fp32.
// ---------------------------------------------------------------------------
__device__ __forceinline__ unsigned bf16rne(float f) {
    const unsigned u = __float_as_uint(f);
    return (u + 0x7FFFu + ((u >> 16) & 1u)) >> 16;
}
__device__ __forceinline__ float bf16tof(unsigned b) {
    return __uint_as_float(b << 16);
}

// split 8 fp32 into three packed bf16x8 fragments (hi, mid, lo)
__device__ __forceinline__ void split8(const float4 a, const float4 b,
                                       bf16x8& h, bf16x8& m, bf16x8& l) {
    float f[8] = {a.x, a.y, a.z, a.w, b.x, b.y, b.z, b.w};
    unsigned hb[8], mb[8], lb[8];
#pragma unroll
    for (int j = 0; j < 8; ++j) {
        const float    x  = f[j];
        const unsigned hu = bf16rne(x);
        const float    r1 = x - bf16tof(hu);
        const unsigned mu = bf16rne(r1);
        const float    r2 = r1 - bf16tof(mu);
        const unsigned lu = bf16rne(r2);
        hb[j] = hu; mb[j] = mu; lb[j] = lu;
    }
    union { unsigned u[4]; bf16x8 v; } H, M, L;
#pragma unroll
    for (int d = 0; d < 4; ++d) {
        H.u[d] = hb[2*d] | (hb[2*d+1] << 16);
        M.u[d] = mb[2*d] | (mb[2*d+1] << 16);
        L.u[d] = lb[2*d] | (lb[2*d+1] << 16);
    }
    h = H.v; m = M.v; l = L.v;
}

// ---------------------------------------------------------------------------
// One-time W conversion: W[64][2048] fp32 -> three bf16 planes [64][2048].
// 131072 elements; trivial cost, runs once before the GEMM on same stream.
// ---------------------------------------------------------------------------
__global__ void convert_w_kernel(const float* __restrict__ w,
                                 ushort_t* __restrict__ whi,
                                 ushort_t* __restrict__ wmid,
                                 ushort_t* __restrict__ wlo)
{
    const int i = (blockIdx.x * 256 + threadIdx.x) * 4;   // grid 128 x 256 = exact
    const float4 v = *(const float4*)(w + i);
    float f[4] = {v.x, v.y, v.z, v.w};
#pragma unroll
    for (int j = 0; j < 4; ++j) {
        const float    x  = f[j];
        const unsigned hu = bf16rne(x);
        const float    r1 = x - bf16tof(hu);
        const unsigned mu = bf16rne(r1);
        const float    r2 = r1 - bf16tof(mu);
        const unsigned lu = bf16rne(r2);
        whi [i + j] = (ushort_t)hu;
        wmid[i + j] = (ushort_t)mu;
        wlo [i + j] = (ushort_t)lu;
    }
}

// ---------------------------------------------------------------------------
// bf16x6 MFMA GEMM: partial[t][ks][e] = sum_{k in quarter ks} x[t][k]*w[e][k]
// computed as (hi+mid+lo)x(hi+mid+lo) keeping the 6 terms >= 2^-18 scale ->
// error ~2^-27 per element, i.e. fp32-equivalent; no top-k flip risk.
//
// Wave-autonomous: no LDS, no barriers. Each wave owns 32 tokens x 64 experts
// x 512 k. Block = 4 independent waves. Grid = 128 token-blocks x 4 k-slices
// = 512 blocks -> 2048 waves = 2/SIMD. A loaded fp32 from global and split
// in-register; B fragments loaded straight from L2-hot pre-converted planes.
//
// MFMA 16x16x32_bf16 layout (m89-verified): A row = lane&15, B col = lane&15,
// k-slots = (lane>>4)-group x 8 contiguous; A and B use the SAME k-slot
// convention so any hardware k-permutation cancels in the contraction.
// C/D: col = lane&15, row = (lane>>4)*4 + reg.
// ---------------------------------------------------------------------------
__global__ __launch_bounds__(256)
void router_gemm_mfma(const float*   __restrict__ x,
                      const ushort_t* __restrict__ whi,
                      const ushort_t* __restrict__ wmid,
                      const ushort_t* __restrict__ wlo,
                      float* __restrict__ partial)
{
    const int tid  = threadIdx.x;
    const int wv   = tid >> 6;
    const int lane = tid & 63;
    const int tb   = blockIdx.x >> 2;        // 0..127 token block (128 tokens)
    const int ks   = blockIdx.x & 3;         // 0..3 k-quarter
    const int t0   = tb * 128 + wv * 32;     // this wave's 32 tokens
    const int k0   = ks * (HDIM / KS_MAIN);  // 512-wide k slice
    const int lr   = lane & 15;              // row (A) / col (B) within tile
    const int lg   = lane >> 4;              // k-group 0..3
    const int kl   = lg * 8;                 // this lane's k offset

    f32x4 acc[2][4];
#pragma unroll
    for (int mt = 0; mt < 2; ++mt)
#pragma unroll
        for (int nt = 0; nt < 4; ++nt) {
            f32x4 z = {0.0f, 0.0f, 0.0f, 0.0f};
            acc[mt][nt] = z;
        }

    const float* px0 = x + (size_t)(t0 + lr) * HDIM + k0 + kl;
    const float* px1 = px0 + (size_t)16 * HDIM;

    const size_t boff = (size_t)lr * HDIM + k0 + kl;
    const ushort_t* pbh = whi  + boff;
    const ushort_t* pbm = wmid + boff;
    const ushort_t* pbl = wlo  + boff;

    for (int kk = 0; kk < HDIM / KS_MAIN; kk += 32) {
        // A: 2 M-tiles x 8 fp32, split to 3 bf16 levels in-register
        const float4 x00 = *(const float4*)(px0 + kk);
        const float4 x01 = *(const float4*)(px0 + kk + 4);
        const float4 x10 = *(const float4*)(px1 + kk);
        const float4 x11 = *(const float4*)(px1 + kk + 4);

        bf16x8 Ah[2], Am[2], Al[2];
        split8(x00, x01, Ah[0], Am[0], Al[0]);
        split8(x10, x11, Ah[1], Am[1], Al[1]);

#pragma unroll
        for (int nt = 0; nt < 4; ++nt) {
            const size_t no = (size_t)nt * 16 * HDIM + kk;
            const bf16x8 Bh = *(const bf16x8*)(pbh + no);
            const bf16x8 Bm = *(const bf16x8*)(pbm + no);
            const bf16x8 Bl = *(const bf16x8*)(pbl + no);
#pragma unroll
            for (int mt = 0; mt < 2; ++mt) {
                // 6 terms: hh + hm + mh + hl + mm + lh  (>= 2^-18 scale)
                acc[mt][nt] = __builtin_amdgcn_mfma_f32_16x16x32_bf16(Ah[mt], Bh, acc[mt][nt], 0, 0, 0);
                acc[mt][nt] = __builtin_amdgcn_mfma_f32_16x16x32_bf16(Am[mt], Bh, acc[mt][nt], 0, 0, 0);
                acc[mt][nt] = __builtin_amdgcn_mfma_f32_16x16x32_bf16(Al[mt], Bh, acc[mt][nt], 0, 0, 0);
                acc[mt][nt] = __builtin_amdgcn_mfma_f32_16x16x32_bf16(Ah[mt], Bm, acc[mt][nt], 0, 0, 0);
                acc[mt][nt] = __builtin_amdgcn_mfma_f32_16x16x32_bf16(Am[mt], Bm, acc[mt][nt], 0, 0, 0);
                acc[mt][nt] = __builtin_amdgcn_mfma_f32_16x16x32_bf16(Ah[mt], Bl, acc[mt][nt], 0, 0, 0);
            }
        }
    }

    // C/D: within-tile row = lg*4 + reg (token), col = lr (expert)
#pragma unroll
    for (int mt = 0; mt < 2; ++mt) {
        const int trow = t0 + mt * 16 + lg * 4;
#pragma unroll
        for (int nt = 0; nt < 4; ++nt) {
            float* pb = partial + ((size_t)trow * KS_MAIN + ks) * NEXP + nt * 16 + lr;
#pragma unroll
            for (int r = 0; r < 4; ++r)
                pb[(size_t)r * KS_MAIN * NEXP] = acc[mt][nt][r];
        }
    }
}

// ---------------------------------------------------------------------------
// Correctness-only fallback (tiny workspace): naive dot per (token, expert).
// ---------------------------------------------------------------------------
__global__ void router_gemm_naive(const float* __restrict__ x,
                                  const float* __restrict__ w,
                                  float* __restrict__ partial)
{
    const int t = blockIdx.x;
    const int e = threadIdx.x;          // 64 threads
    const float* xp = x + (size_t)t * HDIM;
    const float* wp = w + (size_t)e * HDIM;
    float s = 0.0f;
    for (int k = 0; k < HDIM; ++k) s = fmaf(xp[k], wp[k], s);
    partial[(size_t)t * NEXP + e] = s;
}

// ---------------------------------------------------------------------------
// Sum KS partials + sigmoid + biased top-8 (desc, ties -> lower idx) +
// renorm * 2.5. One wave per token, lane = expert.
// ---------------------------------------------------------------------------
template<int KS>
__global__ __launch_bounds__(256)
void router_topk_kernel(const float* __restrict__ partial,
                        const float* __restrict__ bias,
                        float* __restrict__ out_scores,
                        float* __restrict__ out_idx)
{
    const int token = blockIdx.x * 4 + (threadIdx.x >> 6);
    const int lane  = threadIdx.x & 63;

    const float* pt = partial + (size_t)token * KS * NEXP + lane;
    float logit = 0.0f;
#pragma unroll
    for (int s = 0; s < KS; ++s) logit += pt[(size_t)s * NEXP];

    const float score = 1.0f / (1.0f + expf(-logit));
    float key = score + bias[lane];

    float myscore = 0.0f;
    int   myidx   = 0;
    float denom   = 0.0f;

#pragma unroll
    for (int r = 0; r < 8; ++r) {
        float bk = key;
        int   bi = lane;
#pragma unroll
        for (int off = 32; off > 0; off >>= 1) {
            const float ok = __shfl_xor(bk, off);
            const int   oi = __shfl_xor(bi, off);
            if (ok > bk || (ok == bk && oi < bi)) { bk = ok; bi = oi; }
        }
        const float wsc = __shfl(score, bi);   // raw (unbiased) winner score
        denom += wsc;
        if (lane == r)  { myscore = wsc; myidx = bi; }
        if (lane == bi) key = -__builtin_inff();
    }

    const float factor = 2.5f / (denom + 1e-20f);
    if (lane < 8) {
        out_scores[(size_t)token * 8 + lane] = myscore * factor;
        out_idx  [(size_t)token * 8 + lane] = (float)myidx;
    }
}

// ---------------------------------------------------------------------------
extern "C" void kernel_launch(void* const* d_in, const int* in_sizes, int n_in,
                              void* d_out, int out_size, void* d_ws, size_t ws_size,
                              hipStream_t stream)
{
    const float* x    = (const float*)d_in[0];   // [4,4096,2048] f32
    const float* bias = (const float*)d_in[1];   // [64] f32
    const float* w    = (const float*)d_in[2];   // [64,2048] f32

    float* out     = (float*)d_out;
    float* partial = (float*)d_ws;

    const size_t partialBytes = (size_t)T_TOTAL * KS_MAIN * NEXP * 4;  // 16 MiB
    const size_t wplaneElems  = (size_t)NEXP * HDIM;                    // 131072
    const size_t needBytes    = partialBytes + 3 * wplaneElems * sizeof(ushort_t);

    if (ws_size >= needBytes) {
        ushort_t* whi  = (ushort_t*)((char*)d_ws + partialBytes);
        ushort_t* wmid = whi  + wplaneElems;
        ushort_t* wlo  = wmid + wplaneElems;

        convert_w_kernel<<<dim3(128), dim3(256), 0, stream>>>(w, whi, wmid, wlo);
        router_gemm_mfma<<<dim3(128 * KS_MAIN), dim3(256), 0, stream>>>(
            x, whi, wmid, wlo, partial);
        router_topk_kernel<KS_MAIN><<<dim3(T_TOTAL / 4), dim3(256), 0, stream>>>(
            partial, bias, out, out + (size_t)T_TOTAL * 8);
    } else {
        router_gemm_naive<<<dim3(T_TOTAL), dim3(64), 0, stream>>>(x, w, partial);
        router_topk_kernel<1><<<dim3(T_TOTAL / 4), dim3(256), 0, stream>>>(
            partial, bias, out, out + (size_t)T_TOTAL * 8);
    }
}

// Round 3
// 246.620 us; speedup vs baseline: 1.0424x; 1.0424x over previous
//
#include <hip/hip_runtime.h>
#include <math.h>

#define T_TOTAL 16384
#define HDIM    2048
#define NEXP    64
#define KS_MAIN 8

typedef unsigned short ushort_t;
using bf16x8 = __attribute__((ext_vector_type(8))) short;
using f32x4  = __attribute__((ext_vector_type(4))) float;

// ---------------------------------------------------------------------------
// fp32 -> bf16 split helpers. x = hi + mid + lo exactly to O(2^-27 |x|):
// residuals (x - hi), (r1 - mid) are exactly representable in fp32.
// ---------------------------------------------------------------------------
__device__ __forceinline__ unsigned bf16rne(float f) {
    const unsigned u = __float_as_uint(f);
    return (u + 0x7FFFu + ((u >> 16) & 1u)) >> 16;
}
__device__ __forceinline__ float bf16tof(unsigned b) {
    return __uint_as_float(b << 16);
}

// split 8 fp32 into three packed bf16x8 fragments (hi, mid, lo)
__device__ __forceinline__ void split8(const float4 a, const float4 b,
                                       bf16x8& h, bf16x8& m, bf16x8& l) {
    float f[8] = {a.x, a.y, a.z, a.w, b.x, b.y, b.z, b.w};
    unsigned hb[8], mb[8], lb[8];
#pragma unroll
    for (int j = 0; j < 8; ++j) {
        const float    x  = f[j];
        const unsigned hu = bf16rne(x);
        const float    r1 = x - bf16tof(hu);
        const unsigned mu = bf16rne(r1);
        const float    r2 = r1 - bf16tof(mu);
        const unsigned lu = bf16rne(r2);
        hb[j] = hu; mb[j] = mu; lb[j] = lu;
    }
    union { unsigned u[4]; bf16x8 v; } H, M, L;
#pragma unroll
    for (int d = 0; d < 4; ++d) {
        H.u[d] = hb[2*d] | (hb[2*d+1] << 16);
        M.u[d] = mb[2*d] | (mb[2*d+1] << 16);
        L.u[d] = lb[2*d] | (lb[2*d+1] << 16);
    }
    h = H.v; m = M.v; l = L.v;
}

// ---------------------------------------------------------------------------
// One-time W conversion: W[64][2048] fp32 -> three bf16 planes [64][2048].
// ---------------------------------------------------------------------------
__global__ void convert_w_kernel(const float* __restrict__ w,
                                 ushort_t* __restrict__ whi,
                                 ushort_t* __restrict__ wmid,
                                 ushort_t* __restrict__ wlo)
{
    const int i = (blockIdx.x * 256 + threadIdx.x) * 4;   // grid 128 x 256 = exact
    const float4 v = *(const float4*)(w + i);
    float f[4] = {v.x, v.y, v.z, v.w};
#pragma unroll
    for (int j = 0; j < 4; ++j) {
        const float    x  = f[j];
        const unsigned hu = bf16rne(x);
        const float    r1 = x - bf16tof(hu);
        const unsigned mu = bf16rne(r1);
        const float    r2 = r1 - bf16tof(mu);
        const unsigned lu = bf16rne(r2);
        whi [i + j] = (ushort_t)hu;
        wmid[i + j] = (ushort_t)mu;
        wlo [i + j] = (ushort_t)lu;
    }
}

// ---------------------------------------------------------------------------
// bf16x6 MFMA GEMM: partial[t][ks][e] = sum_{k in slice ks} x[t][k]*w[e][k].
// 6 terms (hh,hm,mh,hl,mm,lh) -> error ~2^-27: fp32-equivalent.
//
// Wave-autonomous, no LDS/barriers. Wave owns 32 tokens x 64 experts x 256 k.
// KS=8 -> grid 128 tb x 8 ks = 1024 blocks = 4 blocks/CU = 16 waves/CU (50%),
// which is exactly the register cap (acc 32 AGPR + ~90 VGPR < 128 unified,
// pinned by __launch_bounds__(256,4)). Explicit 1-deep A prefetch (register-
// only, no LDS coupling -> compiler cannot usefully sink it); B fragments
// loaded per-nt from the L2-resident pre-split planes (768 KB total).
//
// MFMA 16x16x32_bf16 layout (m89): A row = lane&15, B col = lane&15, k-slot
// group = lane>>4 (same convention both operands -> HW k-permutation cancels).
// C/D: col = lane&15, row = (lane>>4)*4 + reg.
// ---------------------------------------------------------------------------
__global__ __launch_bounds__(256, 4)
void router_gemm_mfma(const float*   __restrict__ x,
                      const ushort_t* __restrict__ whi,
                      const ushort_t* __restrict__ wmid,
                      const ushort_t* __restrict__ wlo,
                      float* __restrict__ partial)
{
    constexpr int KSLICE = HDIM / KS_MAIN;   // 256
    const int tid  = threadIdx.x;
    const int wv   = tid >> 6;
    const int lane = tid & 63;
    const int tb   = blockIdx.x >> 3;        // 0..127 token block (128 tokens)
    const int ks   = blockIdx.x & 7;         // 0..7 k-slice
    const int t0   = tb * 128 + wv * 32;     // this wave's 32 tokens
    const int k0   = ks * KSLICE;
    const int lr   = lane & 15;              // row (A) / col (B) within tile
    const int lg   = lane >> 4;              // k-group 0..3
    const int kl   = lg * 8;                 // this lane's k offset

    f32x4 acc[2][4];
#pragma unroll
    for (int mt = 0; mt < 2; ++mt)
#pragma unroll
        for (int nt = 0; nt < 4; ++nt) {
            f32x4 z = {0.0f, 0.0f, 0.0f, 0.0f};
            acc[mt][nt] = z;
        }

    const float* px0 = x + (size_t)(t0 + lr) * HDIM + k0 + kl;
    const float* px1 = px0 + (size_t)16 * HDIM;

    const size_t boff = (size_t)lr * HDIM + k0 + kl;
    const ushort_t* pbh = whi  + boff;
    const ushort_t* pbm = wmid + boff;
    const ushort_t* pbl = wlo  + boff;

    // prologue: A tile 0 in registers
    float4 c00 = *(const float4*)(px0);
    float4 c01 = *(const float4*)(px0 + 4);
    float4 c10 = *(const float4*)(px1);
    float4 c11 = *(const float4*)(px1 + 4);

#pragma unroll 1
    for (int kk = 0; kk < KSLICE; kk += 32) {
        // split current A while next A-loads fly
        bf16x8 Ah[2], Am[2], Al[2];
        split8(c00, c01, Ah[0], Am[0], Al[0]);
        split8(c10, c11, Ah[1], Am[1], Al[1]);

        // prefetch next A tile (register-only; issued before B-dependent MFMAs)
        if (kk + 32 < KSLICE) {
            c00 = *(const float4*)(px0 + kk + 32);
            c01 = *(const float4*)(px0 + kk + 36);
            c10 = *(const float4*)(px1 + kk + 32);
            c11 = *(const float4*)(px1 + kk + 36);
        }

#pragma unroll
        for (int nt = 0; nt < 4; ++nt) {
            const size_t no = (size_t)nt * 16 * HDIM + kk;
            const bf16x8 Bh = *(const bf16x8*)(pbh + no);
            const bf16x8 Bm = *(const bf16x8*)(pbm + no);
            const bf16x8 Bl = *(const bf16x8*)(pbl + no);
#pragma unroll
            for (int mt = 0; mt < 2; ++mt) {
                acc[mt][nt] = __builtin_amdgcn_mfma_f32_16x16x32_bf16(Ah[mt], Bh, acc[mt][nt], 0, 0, 0);
                acc[mt][nt] = __builtin_amdgcn_mfma_f32_16x16x32_bf16(Am[mt], Bh, acc[mt][nt], 0, 0, 0);
                acc[mt][nt] = __builtin_amdgcn_mfma_f32_16x16x32_bf16(Al[mt], Bh, acc[mt][nt], 0, 0, 0);
                acc[mt][nt] = __builtin_amdgcn_mfma_f32_16x16x32_bf16(Ah[mt], Bm, acc[mt][nt], 0, 0, 0);
                acc[mt][nt] = __builtin_amdgcn_mfma_f32_16x16x32_bf16(Am[mt], Bm, acc[mt][nt], 0, 0, 0);
                acc[mt][nt] = __builtin_amdgcn_mfma_f32_16x16x32_bf16(Ah[mt], Bl, acc[mt][nt], 0, 0, 0);
            }
        }
    }

    // C/D: within-tile row = lg*4 + reg (token), col = lr (expert)
#pragma unroll
    for (int mt = 0; mt < 2; ++mt) {
        const int trow = t0 + mt * 16 + lg * 4;
#pragma unroll
        for (int nt = 0; nt < 4; ++nt) {
            float* pb = partial + ((size_t)trow * KS_MAIN + ks) * NEXP + nt * 16 + lr;
#pragma unroll
            for (int r = 0; r < 4; ++r)
                pb[(size_t)r * KS_MAIN * NEXP] = acc[mt][nt][r];
        }
    }
}

// ---------------------------------------------------------------------------
// Correctness-only fallback (tiny workspace): naive dot per (token, expert).
// ---------------------------------------------------------------------------
__global__ void router_gemm_naive(const float* __restrict__ x,
                                  const float* __restrict__ w,
                                  float* __restrict__ partial)
{
    const int t = blockIdx.x;
    const int e = threadIdx.x;          // 64 threads
    const float* xp = x + (size_t)t * HDIM;
    const float* wp = w + (size_t)e * HDIM;
    float s = 0.0f;
    for (int k = 0; k < HDIM; ++k) s = fmaf(xp[k], wp[k], s);
    partial[(size_t)t * NEXP + e] = s;
}

// ---------------------------------------------------------------------------
// Sum KS partials + sigmoid + biased top-8 (desc, ties -> lower idx) +
// renorm * 2.5. One wave per token, lane = expert. KS templated -> the
// reduction loop fully unrolls, 8 independent loads in flight.
// ---------------------------------------------------------------------------
template<int KS>
__global__ __launch_bounds__(256)
void router_topk_kernel(const float* __restrict__ partial,
                        const float* __restrict__ bias,
                        float* __restrict__ out_scores,
                        float* __restrict__ out_idx)
{
    const int token = blockIdx.x * 4 + (threadIdx.x >> 6);
    const int lane  = threadIdx.x & 63;

    const float* pt = partial + (size_t)token * KS * NEXP + lane;
    float logit = 0.0f;
#pragma unroll
    for (int s = 0; s < KS; ++s) logit += pt[(size_t)s * NEXP];

    const float score = 1.0f / (1.0f + expf(-logit));
    float key = score + bias[lane];

    float myscore = 0.0f;
    int   myidx   = 0;
    float denom   = 0.0f;

#pragma unroll
    for (int r = 0; r < 8; ++r) {
        float bk = key;
        int   bi = lane;
#pragma unroll
        for (int off = 32; off > 0; off >>= 1) {
            const float ok = __shfl_xor(bk, off);
            const int   oi = __shfl_xor(bi, off);
            if (ok > bk || (ok == bk && oi < bi)) { bk = ok; bi = oi; }
        }
        const float wsc = __shfl(score, bi);   // raw (unbiased) winner score
        denom += wsc;
        if (lane == r)  { myscore = wsc; myidx = bi; }
        if (lane == bi) key = -__builtin_inff();
    }

    const float factor = 2.5f / (denom + 1e-20f);
    if (lane < 8) {
        out_scores[(size_t)token * 8 + lane] = myscore * factor;
        out_idx  [(size_t)token * 8 + lane] = (float)myidx;
    }
}

// ---------------------------------------------------------------------------
extern "C" void kernel_launch(void* const* d_in, const int* in_sizes, int n_in,
                              void* d_out, int out_size, void* d_ws, size_t ws_size,
                              hipStream_t stream)
{
    const float* x    = (const float*)d_in[0];   // [4,4096,2048] f32
    const float* bias = (const float*)d_in[1];   // [64] f32
    const float* w    = (const float*)d_in[2];   // [64,2048] f32

    float* out     = (float*)d_out;
    float* partial = (float*)d_ws;

    const size_t partialBytes = (size_t)T_TOTAL * KS_MAIN * NEXP * 4;   // 32 MiB
    const size_t wplaneElems  = (size_t)NEXP * HDIM;                     // 131072
    const size_t needBytes    = partialBytes + 3 * wplaneElems * sizeof(ushort_t);

    if (ws_size >= needBytes) {
        ushort_t* whi  = (ushort_t*)((char*)d_ws + partialBytes);
        ushort_t* wmid = whi  + wplaneElems;
        ushort_t* wlo  = wmid + wplaneElems;

        convert_w_kernel<<<dim3(128), dim3(256), 0, stream>>>(w, whi, wmid, wlo);
        router_gemm_mfma<<<dim3(128 * KS_MAIN), dim3(256), 0, stream>>>(
            x, whi, wmid, wlo, partial);
        router_topk_kernel<KS_MAIN><<<dim3(T_TOTAL / 4), dim3(256), 0, stream>>>(
            partial, bias, out, out + (size_t)T_TOTAL * 8);
    } else {
        router_gemm_naive<<<dim3(T_TOTAL), dim3(64), 0, stream>>>(x, w, partial);
        router_topk_kernel<1><<<dim3(T_TOTAL / 4), dim3(256), 0, stream>>>(
            partial, bias, out, out + (size_t)T_TOTAL * 8);
    }
}

// Round 4
// 233.837 us; speedup vs baseline: 1.0994x; 1.0547x over previous
//
#include <hip/hip_runtime.h>
#include <math.h>

#define T_TOTAL 16384
#define HDIM    2048
#define NEXP    64
#define KS_MAIN 8

typedef unsigned short ushort_t;
using bf16x8 = __attribute__((ext_vector_type(8))) short;
using f32x4  = __attribute__((ext_vector_type(4))) float;

// ---------------------------------------------------------------------------
// fp32 -> bf16 split helpers. x = hi + mid + lo with residuals exact in fp32
// (Sterbenz: hi within 2^-8 of x). Error of dropped terms ~2^-27 |x| -> the
// 6-term MFMA contraction is fp32-equivalent.
// ---------------------------------------------------------------------------
__device__ __forceinline__ unsigned bf16rne(float f) {
    const unsigned u = __float_as_uint(f);
    return (u + 0x7FFFu + ((u >> 16) & 1u)) >> 16;
}
__device__ __forceinline__ float bf16tof(unsigned b) {
    return __uint_as_float(b << 16);
}

// packed 2x fp32 -> 2x bf16 (RNE), 1 instr. Pure-VALU asm: no memory
// operands, safe to let the scheduler move it (rule-18 hazard is ds_read-
// specific). dst.lo = bf16(a), dst.hi = bf16(b).
__device__ __forceinline__ unsigned cvtpk_bf16(float a, float b) {
    unsigned r;
    asm("v_cvt_pk_bf16_f32 %0, %1, %2" : "=v"(r) : "v"(a), "v"(b));
    return r;
}

// split 8 fp32 into three packed bf16x8 fragments (hi, mid, lo)
__device__ __forceinline__ void split8(const float4 a, const float4 b,
                                       bf16x8& h, bf16x8& m, bf16x8& l) {
    const float f[8] = {a.x, a.y, a.z, a.w, b.x, b.y, b.z, b.w};
    union { unsigned u[4]; bf16x8 v; } H, M, L;
#pragma unroll
    for (int d = 0; d < 4; ++d) {
        const float f0 = f[2*d], f1 = f[2*d+1];
        const unsigned ph = cvtpk_bf16(f0, f1);
        const float r0 = f0 - __uint_as_float(ph << 16);
        const float r1 = f1 - __uint_as_float(ph & 0xFFFF0000u);
        const unsigned pm = cvtpk_bf16(r0, r1);
        const float s0 = r0 - __uint_as_float(pm << 16);
        const float s1 = r1 - __uint_as_float(pm & 0xFFFF0000u);
        H.u[d] = ph;
        M.u[d] = pm;
        L.u[d] = cvtpk_bf16(s0, s1);
    }
    h = H.v; m = M.v; l = L.v;
}

// ---------------------------------------------------------------------------
// One-time W conversion: W[64][2048] fp32 -> three bf16 planes [64][2048].
// NOTE: planes must stay contiguous (whi|wmid|wlo) — the GEMM's B prefetch
// may read a few elements past a plane's end on the last k-slice (values
// unused; address must stay mapped).
// ---------------------------------------------------------------------------
__global__ void convert_w_kernel(const float* __restrict__ w,
                                 ushort_t* __restrict__ whi,
                                 ushort_t* __restrict__ wmid,
                                 ushort_t* __restrict__ wlo)
{
    const int i = (blockIdx.x * 256 + threadIdx.x) * 4;   // grid 128 x 256 = exact
    const float4 v = *(const float4*)(w + i);
    float f[4] = {v.x, v.y, v.z, v.w};
#pragma unroll
    for (int j = 0; j < 4; ++j) {
        const float    x  = f[j];
        const unsigned hu = bf16rne(x);
        const float    r1 = x - bf16tof(hu);
        const unsigned mu = bf16rne(r1);
        const float    r2 = r1 - bf16tof(mu);
        const unsigned lu = bf16rne(r2);
        whi [i + j] = (ushort_t)hu;
        wmid[i + j] = (ushort_t)mu;
        wlo [i + j] = (ushort_t)lu;
    }
}

// ---------------------------------------------------------------------------
// bf16x6 MFMA GEMM: partial[t][ks][e] = sum_{k in slice ks} x[t][k]*w[e][k].
// 6 terms (hh,hm,mh,hl,mm,lh) -> error ~2^-27: fp32-equivalent.
//
// Wave-autonomous, no LDS/barriers. Wave owns 32 tokens x 64 experts x 256 k.
// Grid 128 tb x 8 ks = 1024 blocks = 4 blocks/CU = 16 waves/CU, pinned at the
// 128-reg unified cap by __launch_bounds__(256,4).
//
// Latency structure per kk-iteration (the round-4 change):
//   split(A cur)  [~100 VALU instr via v_cvt_pk_bf16_f32]
//   issue A(kk+32) loads            — covered by the whole nt loop + split
//   nt = 0..3:  issue B(nt+1) loads — covered by nt's 12 MFMAs (+3 waves)
//               12 x mfma_16x16x32_bf16 on B(nt)
// B fragments rotate through named registers (no runtime-indexed arrays).
//
// MFMA 16x16x32_bf16 layout (m89): A row = lane&15, B col = lane&15, k-group
// = lane>>4 (same convention both operands -> HW k-permutation cancels).
// C/D: col = lane&15, row = (lane>>4)*4 + reg.
// ---------------------------------------------------------------------------
__global__ __launch_bounds__(256, 4)
void router_gemm_mfma(const float*   __restrict__ x,
                      const ushort_t* __restrict__ whi,
                      const ushort_t* __restrict__ wmid,
                      const ushort_t* __restrict__ wlo,
                      float* __restrict__ partial)
{
    constexpr int KSLICE = HDIM / KS_MAIN;   // 256
    const int tid  = threadIdx.x;
    const int wv   = tid >> 6;
    const int lane = tid & 63;
    const int tb   = blockIdx.x >> 3;        // 0..127 token block (128 tokens)
    const int ks   = blockIdx.x & 7;         // 0..7 k-slice
    const int t0   = tb * 128 + wv * 32;     // this wave's 32 tokens
    const int k0   = ks * KSLICE;
    const int lr   = lane & 15;              // row (A) / col (B) within tile
    const int lg   = lane >> 4;              // k-group 0..3
    const int kl   = lg * 8;                 // this lane's k offset

    f32x4 acc[2][4];
#pragma unroll
    for (int mt = 0; mt < 2; ++mt)
#pragma unroll
        for (int nt = 0; nt < 4; ++nt) {
            f32x4 z = {0.0f, 0.0f, 0.0f, 0.0f};
            acc[mt][nt] = z;
        }

    const float* px0 = x + (size_t)(t0 + lr) * HDIM + k0 + kl;
    const float* px1 = px0 + (size_t)16 * HDIM;

    const size_t boff = (size_t)lr * HDIM + k0 + kl;
    const ushort_t* pbh = whi  + boff;
    const ushort_t* pbm = wmid + boff;
    const ushort_t* pbl = wlo  + boff;

    // prologue: A tile 0 and B fragment (kk=0, nt=0)
    float4 c00 = *(const float4*)(px0);
    float4 c01 = *(const float4*)(px0 + 4);
    float4 c10 = *(const float4*)(px1);
    float4 c11 = *(const float4*)(px1 + 4);

    bf16x8 Bh_c = *(const bf16x8*)(pbh);
    bf16x8 Bm_c = *(const bf16x8*)(pbm);
    bf16x8 Bl_c = *(const bf16x8*)(pbl);

#pragma unroll 1
    for (int kk = 0; kk < KSLICE; kk += 32) {
        // split current A (cheap now: cvt_pk), then reuse the regs for the
        // next tile's loads so the compiler cannot sink them to their use
        bf16x8 Ah[2], Am[2], Al[2];
        split8(c00, c01, Ah[0], Am[0], Al[0]);
        split8(c10, c11, Ah[1], Am[1], Al[1]);

        if (kk + 32 < KSLICE) {
            c00 = *(const float4*)(px0 + kk + 32);
            c01 = *(const float4*)(px0 + kk + 36);
            c10 = *(const float4*)(px1 + kk + 32);
            c11 = *(const float4*)(px1 + kk + 36);
        }

#pragma unroll
        for (int nt = 0; nt < 4; ++nt) {
            // prefetch next B fragment group (nt+1, or nt=0 of kk+32;
            // clamp the final-out-of-range case back to a valid address)
            const int ntn = (nt + 1) & 3;
            int kkn = (nt == 3) ? kk + 32 : kk;
            if (kkn >= KSLICE) kkn = 0;
            const size_t non = (size_t)ntn * 16 * HDIM + kkn;
            bf16x8 Bh_n = *(const bf16x8*)(pbh + non);
            bf16x8 Bm_n = *(const bf16x8*)(pbm + non);
            bf16x8 Bl_n = *(const bf16x8*)(pbl + non);

#pragma unroll
            for (int mt = 0; mt < 2; ++mt) {
                acc[mt][nt] = __builtin_amdgcn_mfma_f32_16x16x32_bf16(Ah[mt], Bh_c, acc[mt][nt], 0, 0, 0);
                acc[mt][nt] = __builtin_amdgcn_mfma_f32_16x16x32_bf16(Am[mt], Bh_c, acc[mt][nt], 0, 0, 0);
                acc[mt][nt] = __builtin_amdgcn_mfma_f32_16x16x32_bf16(Al[mt], Bh_c, acc[mt][nt], 0, 0, 0);
                acc[mt][nt] = __builtin_amdgcn_mfma_f32_16x16x32_bf16(Ah[mt], Bm_c, acc[mt][nt], 0, 0, 0);
                acc[mt][nt] = __builtin_amdgcn_mfma_f32_16x16x32_bf16(Am[mt], Bm_c, acc[mt][nt], 0, 0, 0);
                acc[mt][nt] = __builtin_amdgcn_mfma_f32_16x16x32_bf16(Ah[mt], Bl_c, acc[mt][nt], 0, 0, 0);
            }

            Bh_c = Bh_n; Bm_c = Bm_n; Bl_c = Bl_n;
        }
    }

    // C/D: within-tile row = lg*4 + reg (token), col = lr (expert)
#pragma unroll
    for (int mt = 0; mt < 2; ++mt) {
        const int trow = t0 + mt * 16 + lg * 4;
#pragma unroll
        for (int nt = 0; nt < 4; ++nt) {
            float* pb = partial + ((size_t)trow * KS_MAIN + ks) * NEXP + nt * 16 + lr;
#pragma unroll
            for (int r = 0; r < 4; ++r)
                pb[(size_t)r * KS_MAIN * NEXP] = acc[mt][nt][r];
        }
    }
}

// ---------------------------------------------------------------------------
// Correctness-only fallback (tiny workspace): naive dot per (token, expert).
// ---------------------------------------------------------------------------
__global__ void router_gemm_naive(const float* __restrict__ x,
                                  const float* __restrict__ w,
                                  float* __restrict__ partial)
{
    const int t = blockIdx.x;
    const int e = threadIdx.x;          // 64 threads
    const float* xp = x + (size_t)t * HDIM;
    const float* wp = w + (size_t)e * HDIM;
    float s = 0.0f;
    for (int k = 0; k < HDIM; ++k) s = fmaf(xp[k], wp[k], s);
    partial[(size_t)t * NEXP + e] = s;
}

// ---------------------------------------------------------------------------
// Sum KS partials + sigmoid + biased top-8 (desc, ties -> lower idx) +
// renorm * 2.5. One wave per token, lane = expert.
// Round-4 change: ballot-based argmax. Butterfly reduces the MAX only
// (6 shfl+fmax); the winning lane set comes from __ballot(key==bk) and the
// lowest set bit is the lowest expert index -> identical tie-break to the
// reference, with ~half the serial shuffle chain of the (key,idx) butterfly.
// ---------------------------------------------------------------------------
template<int KS>
__global__ __launch_bounds__(256)
void router_topk_kernel(const float* __restrict__ partial,
                        const float* __restrict__ bias,
                        float* __restrict__ out_scores,
                        float* __restrict__ out_idx)
{
    const int token = blockIdx.x * 4 + (threadIdx.x >> 6);
    const int lane  = threadIdx.x & 63;

    const float* pt = partial + (size_t)token * KS * NEXP + lane;
    float logit = 0.0f;
#pragma unroll
    for (int s = 0; s < KS; ++s) logit += pt[(size_t)s * NEXP];

    const float score = 1.0f / (1.0f + expf(-logit));
    float key = score + bias[lane];

    float myscore = 0.0f;
    int   myidx   = 0;
    float denom   = 0.0f;

#pragma unroll
    for (int r = 0; r < 8; ++r) {
        float bk = key;
#pragma unroll
        for (int off = 32; off > 0; off >>= 1)
            bk = fmaxf(bk, __shfl_xor(bk, off));
        const unsigned long long msk = __ballot(key == bk);
        const int bi = __ffsll(msk) - 1;          // lowest tied expert idx
        const float wsc = __shfl(score, bi);      // raw (unbiased) winner score
        denom += wsc;
        if (lane == r)  { myscore = wsc; myidx = bi; }
        if (lane == bi) key = -__builtin_inff();
    }

    const float factor = 2.5f / (denom + 1e-20f);
    if (lane < 8) {
        out_scores[(size_t)token * 8 + lane] = myscore * factor;
        out_idx  [(size_t)token * 8 + lane] = (float)myidx;
    }
}

// ---------------------------------------------------------------------------
extern "C" void kernel_launch(void* const* d_in, const int* in_sizes, int n_in,
                              void* d_out, int out_size, void* d_ws, size_t ws_size,
                              hipStream_t stream)
{
    const float* x    = (const float*)d_in[0];   // [4,4096,2048] f32
    const float* bias = (const float*)d_in[1];   // [64] f32
    const float* w    = (const float*)d_in[2];   // [64,2048] f32

    float* out     = (float*)d_out;
    float* partial = (float*)d_ws;

    const size_t partialBytes = (size_t)T_TOTAL * KS_MAIN * NEXP * 4;   // 32 MiB
    const size_t wplaneElems  = (size_t)NEXP * HDIM;                     // 131072
    const size_t needBytes    = partialBytes + 3 * wplaneElems * sizeof(ushort_t);

    if (ws_size >= needBytes) {
        ushort_t* whi  = (ushort_t*)((char*)d_ws + partialBytes);
        ushort_t* wmid = whi  + wplaneElems;
        ushort_t* wlo  = wmid + wplaneElems;

        convert_w_kernel<<<dim3(128), dim3(256), 0, stream>>>(w, whi, wmid, wlo);
        router_gemm_mfma<<<dim3(128 * KS_MAIN), dim3(256), 0, stream>>>(
            x, whi, wmid, wlo, partial);
        router_topk_kernel<KS_MAIN><<<dim3(T_TOTAL / 4), dim3(256), 0, stream>>>(
            partial, bias, out, out + (size_t)T_TOTAL * 8);
    } else {
        router_gemm_naive<<<dim3(T_TOTAL), dim3(64), 0, stream>>>(x, w, partial);
        router_topk_kernel<1><<<dim3(T_TOTAL / 4), dim3(256), 0, stream>>>(
            partial, bias, out, out + (size_t)T_TOTAL * 8);
    }
}

// Round 5
// 229.158 us; speedup vs baseline: 1.1219x; 1.0204x over previous
//
#include <hip/hip_runtime.h>
#include <math.h>

#define T_TOTAL 16384
#define HDIM    2048
#define NEXP    64
#define KS_MAIN 8

typedef unsigned short ushort_t;
using bf16x8 = __attribute__((ext_vector_type(8))) short;
using f32x4  = __attribute__((ext_vector_type(4))) float;

// ---------------------------------------------------------------------------
// fp32 -> bf16 split helpers. x = hi + mid + lo with residuals exact in fp32.
// Dropped terms ~2^-27 |x| -> 6-term MFMA contraction is fp32-equivalent.
// ---------------------------------------------------------------------------
__device__ __forceinline__ unsigned bf16rne(float f) {
    const unsigned u = __float_as_uint(f);
    return (u + 0x7FFFu + ((u >> 16) & 1u)) >> 16;
}
__device__ __forceinline__ float bf16tof(unsigned b) {
    return __uint_as_float(b << 16);
}

// packed 2x fp32 -> 2x bf16 (RNE), 1 instr (pure VALU, safe to reschedule)
__device__ __forceinline__ unsigned cvtpk_bf16(float a, float b) {
    unsigned r;
    asm("v_cvt_pk_bf16_f32 %0, %1, %2" : "=v"(r) : "v"(a), "v"(b));
    return r;
}

// split 8 fp32 into three packed bf16x8 fragments (hi, mid, lo)
__device__ __forceinline__ void split8(const float4 a, const float4 b,
                                       bf16x8& h, bf16x8& m, bf16x8& l) {
    const float f[8] = {a.x, a.y, a.z, a.w, b.x, b.y, b.z, b.w};
    union { unsigned u[4]; bf16x8 v; } H, M, L;
#pragma unroll
    for (int d = 0; d < 4; ++d) {
        const float f0 = f[2*d], f1 = f[2*d+1];
        const unsigned ph = cvtpk_bf16(f0, f1);
        const float r0 = f0 - __uint_as_float(ph << 16);
        const float r1 = f1 - __uint_as_float(ph & 0xFFFF0000u);
        const unsigned pm = cvtpk_bf16(r0, r1);
        const float s0 = r0 - __uint_as_float(pm << 16);
        const float s1 = r1 - __uint_as_float(pm & 0xFFFF0000u);
        H.u[d] = ph;
        M.u[d] = pm;
        L.u[d] = cvtpk_bf16(s0, s1);
    }
    h = H.v; m = M.v; l = L.v;
}

// async global->LDS, 16B per lane: lane i lands at ldsbase + 16*i
__device__ __forceinline__ void load_lds16(const float* g, float* lds) {
    __builtin_amdgcn_global_load_lds(
        (const __attribute__((address_space(1))) unsigned int*)g,
        (__attribute__((address_space(3))) unsigned int*)lds, 16, 0, 0);
}

// ---------------------------------------------------------------------------
// One-time W conversion: W[64][2048] fp32 -> three bf16 planes [64][2048].
// Planes stay contiguous (whi|wmid|wlo): GEMM's B prefetch may read a few
// elements past a plane's end (values unused; address stays mapped).
// ---------------------------------------------------------------------------
__global__ void convert_w_kernel(const float* __restrict__ w,
                                 ushort_t* __restrict__ whi,
                                 ushort_t* __restrict__ wmid,
                                 ushort_t* __restrict__ wlo)
{
    const int i = (blockIdx.x * 256 + threadIdx.x) * 4;   // grid 128 x 256 = exact
    const float4 v = *(const float4*)(w + i);
    float f[4] = {v.x, v.y, v.z, v.w};
#pragma unroll
    for (int j = 0; j < 4; ++j) {
        const float    x  = f[j];
        const unsigned hu = bf16rne(x);
        const float    r1 = x - bf16tof(hu);
        const unsigned mu = bf16rne(r1);
        const float    r2 = r1 - bf16tof(mu);
        const unsigned lu = bf16rne(r2);
        whi [i + j] = (ushort_t)hu;
        wmid[i + j] = (ushort_t)mu;
        wlo [i + j] = (ushort_t)lu;
    }
}

// ---------------------------------------------------------------------------
// bf16x6 MFMA GEMM, round-5 structure: X staged via global_load_lds (m97
// path) into double-buffered LDS; B register-rotated from L2-hot planes.
//
//   LDS X layout: [buf][128 rows][32 f32], row stride 128 B, NO padding
//   (DMA writes linearly). Bank-conflict fix is the rule-21 pair:
//     - DMA source: lane i loads global chunk c = (i&7) ^ (i>>3 & 7), so
//       LDS slot s of row r holds global chunk s ^ (r&7)  (involution)
//     - reader: chunk g of row r is at slot g ^ (r&7)
//   Read pattern check: bank-group = (2lg ^ (lr&7)) -> 8 lanes per 4-bank
//   group = uniform minimum aliasing = conflict-free.
//
// Per kk-iter: issue next tile's 4 DMA instrs, compute current tile
// (4 ds_read_b128 + 2 split8 + 12 B-loads + 48 MFMA), one barrier.
// Grid 128 tb x 8 ks = 1024 blocks; LDS 32 KB -> 4 blocks/CU; VGPR<=128
// pinned by __launch_bounds__(256,4).
//
// MFMA 16x16x32_bf16 layout (m89): A row = lane&15, B col = lane&15, k-group
// = lane>>4 (same convention both operands). C/D: col=lane&15,
// row=(lane>>4)*4+reg.
// ---------------------------------------------------------------------------
__global__ __launch_bounds__(256, 4)
void router_gemm_mfma(const float*   __restrict__ x,
                      const ushort_t* __restrict__ whi,
                      const ushort_t* __restrict__ wmid,
                      const ushort_t* __restrict__ wlo,
                      float* __restrict__ partial)
{
    constexpr int KSLICE = HDIM / KS_MAIN;   // 256
    __shared__ __align__(16) float Xs[2][128 * 32];   // 32 KB

    const int tid  = threadIdx.x;
    const int wv   = tid >> 6;
    const int lane = tid & 63;
    const int tb   = blockIdx.x >> 3;        // 0..127 token block (128 tokens)
    const int ks   = blockIdx.x & 7;         // 0..7 k-slice
    const int t0   = tb * 128 + wv * 32;     // this wave's 32 tokens
    const int k0   = ks * KSLICE;
    const int lr   = lane & 15;              // row (A) / col (B) within tile
    const int lg   = lane >> 4;              // k-group 0..3

    // DMA staging geometry: instr p stages rows (wv*32 + p*8 + (lane>>3)),
    // lane slot = lane&7, pre-swizzled global chunk = slot ^ (lane>>3)
    const int r8 = lane >> 3;                // 0..7 (== row&7 since p*8 = 0 mod 8)
    const int cc = (lane & 7) ^ r8;          // global 16B-chunk index
    const float* xg = x + (size_t)(t0 + r8) * HDIM + k0 + cc * 4;

    f32x4 acc[2][4];
#pragma unroll
    for (int mt = 0; mt < 2; ++mt)
#pragma unroll
        for (int nt = 0; nt < 4; ++nt) {
            f32x4 z = {0.0f, 0.0f, 0.0f, 0.0f};
            acc[mt][nt] = z;
        }

    const size_t boff = (size_t)lr * HDIM + k0 + lg * 8;
    const ushort_t* pbh = whi  + boff;
    const ushort_t* pbm = wmid + boff;
    const ushort_t* pbl = wlo  + boff;

    // prologue: stage X tile 0 into buf 0; B fragment (kk=0, nt=0) into regs
#pragma unroll
    for (int p = 0; p < 4; ++p)
        load_lds16(xg + (size_t)(p * 8) * HDIM, &Xs[0][(wv * 32 + p * 8) * 32]);

    bf16x8 Bh_c = *(const bf16x8*)(pbh);
    bf16x8 Bm_c = *(const bf16x8*)(pbm);
    bf16x8 Bl_c = *(const bf16x8*)(pbl);

    __syncthreads();                         // buf0 DMA drained + all waves

    int cur = 0;
#pragma unroll 1
    for (int kk = 0; kk < KSLICE; kk += 32) {
        // issue next tile's DMA now; lands during this tile's compute
        if (kk + 32 < KSLICE) {
            const float* xn = xg + kk + 32;
#pragma unroll
            for (int p = 0; p < 4; ++p)
                load_lds16(xn + (size_t)(p * 8) * HDIM,
                           &Xs[cur ^ 1][(wv * 32 + p * 8) * 32]);
        }

        // A fragments from LDS (swizzled slots), split to 3 bf16 levels
        bf16x8 Ah[2], Am[2], Al[2];
#pragma unroll
        for (int mt = 0; mt < 2; ++mt) {
            const int row  = mt * 16 + lr;                  // wave-local row
            const int sw   = row & 7;
            const float* rb = &Xs[cur][(wv * 32 + row) * 32];
            const float4 c0 = *(const float4*)(rb + (((2 * lg)     ^ sw) * 4));
            const float4 c1 = *(const float4*)(rb + (((2 * lg + 1) ^ sw) * 4));
            split8(c0, c1, Ah[mt], Am[mt], Al[mt]);
        }

#pragma unroll
        for (int nt = 0; nt < 4; ++nt) {
            // prefetch next B fragment group (nt+1, or nt0 of kk+32; clamp)
            const int ntn = (nt + 1) & 3;
            int kkn = (nt == 3) ? kk + 32 : kk;
            if (kkn >= KSLICE) kkn = 0;
            const size_t non = (size_t)ntn * 16 * HDIM + kkn;
            bf16x8 Bh_n = *(const bf16x8*)(pbh + non);
            bf16x8 Bm_n = *(const bf16x8*)(pbm + non);
            bf16x8 Bl_n = *(const bf16x8*)(pbl + non);

#pragma unroll
            for (int mt = 0; mt < 2; ++mt) {
                acc[mt][nt] = __builtin_amdgcn_mfma_f32_16x16x32_bf16(Ah[mt], Bh_c, acc[mt][nt], 0, 0, 0);
                acc[mt][nt] = __builtin_amdgcn_mfma_f32_16x16x32_bf16(Am[mt], Bh_c, acc[mt][nt], 0, 0, 0);
                acc[mt][nt] = __builtin_amdgcn_mfma_f32_16x16x32_bf16(Al[mt], Bh_c, acc[mt][nt], 0, 0, 0);
                acc[mt][nt] = __builtin_amdgcn_mfma_f32_16x16x32_bf16(Ah[mt], Bm_c, acc[mt][nt], 0, 0, 0);
                acc[mt][nt] = __builtin_amdgcn_mfma_f32_16x16x32_bf16(Am[mt], Bm_c, acc[mt][nt], 0, 0, 0);
                acc[mt][nt] = __builtin_amdgcn_mfma_f32_16x16x32_bf16(Ah[mt], Bl_c, acc[mt][nt], 0, 0, 0);
            }
            Bh_c = Bh_n; Bm_c = Bm_n; Bl_c = Bl_n;
        }

        // barrier: next-tile DMA drained (implicit vmcnt(0)) + cur reads done
        __syncthreads();
        cur ^= 1;
    }

    // C/D: within-tile row = lg*4 + reg (token), col = lr (expert)
#pragma unroll
    for (int mt = 0; mt < 2; ++mt) {
        const int trow = t0 + mt * 16 + lg * 4;
#pragma unroll
        for (int nt = 0; nt < 4; ++nt) {
            float* pb = partial + ((size_t)trow * KS_MAIN + ks) * NEXP + nt * 16 + lr;
#pragma unroll
            for (int r = 0; r < 4; ++r)
                pb[(size_t)r * KS_MAIN * NEXP] = acc[mt][nt][r];
        }
    }
}

// ---------------------------------------------------------------------------
// Correctness-only fallback (tiny workspace): naive dot per (token, expert).
// ---------------------------------------------------------------------------
__global__ void router_gemm_naive(const float* __restrict__ x,
                                  const float* __restrict__ w,
                                  float* __restrict__ partial)
{
    const int t = blockIdx.x;
    const int e = threadIdx.x;          // 64 threads
    const float* xp = x + (size_t)t * HDIM;
    const float* wp = w + (size_t)e * HDIM;
    float s = 0.0f;
    for (int k = 0; k < HDIM; ++k) s = fmaf(xp[k], wp[k], s);
    partial[(size_t)t * NEXP + e] = s;
}

// ---------------------------------------------------------------------------
// Sum KS partials + sigmoid + biased top-8 (desc, ties -> lower idx) +
// renorm * 2.5. One wave per token, lane = expert. Ballot-argmax: butterfly
// reduces max only; __ballot(key==bk) + lowest set bit reproduces the
// lowest-index tie-break exactly.
// ---------------------------------------------------------------------------
template<int KS>
__global__ __launch_bounds__(256)
void router_topk_kernel(const float* __restrict__ partial,
                        const float* __restrict__ bias,
                        float* __restrict__ out_scores,
                        float* __restrict__ out_idx)
{
    const int token = blockIdx.x * 4 + (threadIdx.x >> 6);
    const int lane  = threadIdx.x & 63;

    const float* pt = partial + (size_t)token * KS * NEXP + lane;
    float logit = 0.0f;
#pragma unroll
    for (int s = 0; s < KS; ++s) logit += pt[(size_t)s * NEXP];

    const float score = 1.0f / (1.0f + expf(-logit));
    float key = score + bias[lane];

    float myscore = 0.0f;
    int   myidx   = 0;
    float denom   = 0.0f;

#pragma unroll
    for (int r = 0; r < 8; ++r) {
        float bk = key;
#pragma unroll
        for (int off = 32; off > 0; off >>= 1)
            bk = fmaxf(bk, __shfl_xor(bk, off));
        const unsigned long long msk = __ballot(key == bk);
        const int bi = __ffsll(msk) - 1;          // lowest tied expert idx
        const float wsc = __shfl(score, bi);      // raw (unbiased) winner score
        denom += wsc;
        if (lane == r)  { myscore = wsc; myidx = bi; }
        if (lane == bi) key = -__builtin_inff();
    }

    const float factor = 2.5f / (denom + 1e-20f);
    if (lane < 8) {
        out_scores[(size_t)token * 8 + lane] = myscore * factor;
        out_idx  [(size_t)token * 8 + lane] = (float)myidx;
    }
}

// ---------------------------------------------------------------------------
extern "C" void kernel_launch(void* const* d_in, const int* in_sizes, int n_in,
                              void* d_out, int out_size, void* d_ws, size_t ws_size,
                              hipStream_t stream)
{
    const float* x    = (const float*)d_in[0];   // [4,4096,2048] f32
    const float* bias = (const float*)d_in[1];   // [64] f32
    const float* w    = (const float*)d_in[2];   // [64,2048] f32

    float* out     = (float*)d_out;
    float* partial = (float*)d_ws;

    const size_t partialBytes = (size_t)T_TOTAL * KS_MAIN * NEXP * 4;   // 32 MiB
    const size_t wplaneElems  = (size_t)NEXP * HDIM;                     // 131072
    const size_t needBytes    = partialBytes + 3 * wplaneElems * sizeof(ushort_t);

    if (ws_size >= needBytes) {
        ushort_t* whi  = (ushort_t*)((char*)d_ws + partialBytes);
        ushort_t* wmid = whi  + wplaneElems;
        ushort_t* wlo  = wmid + wplaneElems;

        convert_w_kernel<<<dim3(128), dim3(256), 0, stream>>>(w, whi, wmid, wlo);
        router_gemm_mfma<<<dim3(128 * KS_MAIN), dim3(256), 0, stream>>>(
            x, whi, wmid, wlo, partial);
        router_topk_kernel<KS_MAIN><<<dim3(T_TOTAL / 4), dim3(256), 0, stream>>>(
            partial, bias, out, out + (size_t)T_TOTAL * 8);
    } else {
        router_gemm_naive<<<dim3(T_TOTAL), dim3(64), 0, stream>>>(x, w, partial);
        router_topk_kernel<1><<<dim3(T_TOTAL / 4), dim3(256), 0, stream>>>(
            partial, bias, out, out + (size_t)T_TOTAL * 8);
    }
}

// Round 6
// 217.016 us; speedup vs baseline: 1.1846x; 1.0560x over previous
//
#include <hip/hip_runtime.h>
#include <math.h>

#define T_TOTAL 16384
#define HDIM    2048
#define NEXP    64

typedef unsigned short ushort_t;
using bf16x8 = __attribute__((ext_vector_type(8))) short;
using f32x4  = __attribute__((ext_vector_type(4))) float;

// ---------------------------------------------------------------------------
// fp32 -> bf16 split: x = hi + mid + lo, residuals exact in fp32; dropped
// cross terms ~2^-27 |x| -> the 6-term MFMA contraction is fp32-equivalent.
// ---------------------------------------------------------------------------
__device__ __forceinline__ unsigned cvtpk_bf16(float a, float b) {
    unsigned r;
    asm("v_cvt_pk_bf16_f32 %0, %1, %2" : "=v"(r) : "v"(a), "v"(b));
    return r;
}

// split 8 fp32 into three packed bf16x8 fragments (hi, mid, lo)
__device__ __forceinline__ void split8(const float4 a, const float4 b,
                                       bf16x8& h, bf16x8& m, bf16x8& l) {
    const float f[8] = {a.x, a.y, a.z, a.w, b.x, b.y, b.z, b.w};
    union { unsigned u[4]; bf16x8 v; } H, M, L;
#pragma unroll
    for (int d = 0; d < 4; ++d) {
        const float f0 = f[2*d], f1 = f[2*d+1];
        const unsigned ph = cvtpk_bf16(f0, f1);
        const float r0 = f0 - __uint_as_float(ph << 16);
        const float r1 = f1 - __uint_as_float(ph & 0xFFFF0000u);
        const unsigned pm = cvtpk_bf16(r0, r1);
        const float s0 = r0 - __uint_as_float(pm << 16);
        const float s1 = r1 - __uint_as_float(pm & 0xFFFF0000u);
        H.u[d] = ph;
        M.u[d] = pm;
        L.u[d] = cvtpk_bf16(s0, s1);
    }
    h = H.v; m = M.v; l = L.v;
}

// async global->LDS, 16B per lane: lane i lands at ldsbase + 16*i
__device__ __forceinline__ void load_lds16(const float* g, float* lds) {
    __builtin_amdgcn_global_load_lds(
        (const __attribute__((address_space(1))) unsigned int*)g,
        (__attribute__((address_space(3))) unsigned int*)lds, 16, 0, 0);
}

// ---------------------------------------------------------------------------
// FUSED router: logits GEMM (bf16x6 MFMA) + sigmoid + biased top-8 + renorm,
// one dispatch, zero workspace.
//
// Grid 512 blocks x 256 thr (4 waves). Block owns 32 tokens; wave wv owns
// K-quarter [wv*512, wv*512+512) as 16 iterations of 32-k.
//
// W path (new this round): per-wave LDS staging of the fp32 W tile
// [64 experts][32 k] (8 KB), double-buffered, via global_load_lds width-16.
//   rule-21 swizzle pair: DMA source chunk = (lane&7) ^ (lane>>3), so LDS
//   slot s of expert-row e holds global chunk s ^ (e&7); reader fetches
//   chunk g at slot g ^ (e&7). Read pattern: slot = 2lg ^ (lr&7) -> 8
//   distinct slots x 2 lanes each = 2-way aliasing = free (m136).
// B fragments are split to bf16x6 in-register per nt -> no convert kernel,
// no bf16 planes, W fp32 (512 KB) stays L2-hot and is read ONCE per wave
// per k-step via DMA (no per-fragment scattered L2 loads).
//
// No barriers in the K-loop: waves autonomous; per-iter counted
// asm s_waitcnt vmcnt(12) (= this iter's 4 A-loads + 8 DMA) guarantees the
// PREVIOUS iter's DMA has landed without ever draining to 0 (T4 idiom).
//
// Epilogue: vmcnt(0) (drain wrapped final DMA), overlay per-wave partial
// logits into LDS, ONE __syncthreads, 4-way sum, sigmoid, ballot-argmax
// top-8 (ties -> lowest idx, exactly the reference), renorm*2.5, store.
//
// MFMA 16x16x32_bf16 (m89): A row = lane&15, B col = lane&15, k-group =
// lane>>4 (same convention both operands). C/D: col=lane&15, row=(lane>>4)*4+reg.
// ---------------------------------------------------------------------------
__global__ __launch_bounds__(256, 2)
void router_fused(const float* __restrict__ x,
                  const float* __restrict__ w,
                  const float* __restrict__ bias,
                  float* __restrict__ out_scores,
                  float* __restrict__ out_idx)
{
    // 64 KB: wave wv owns S[wv*4096 .. +4096) = two 2048-float W buffers.
    // After the GEMM phase, S[p*4096 + t*64 + e] overlays partial logits.
    __shared__ __align__(16) float S[4 * 4096];

    const int tid  = threadIdx.x;
    const int wv   = tid >> 6;
    const int lane = tid & 63;
    const int t0   = blockIdx.x * 32;        // this block's 32 tokens
    const int k0   = wv * 512;               // this wave's K-quarter
    const int lr   = lane & 15;
    const int lg   = lane >> 4;

    float* Wbase = S + wv * 4096;

    // W DMA geometry: instr p stages expert rows p*8 + (lane>>3);
    // slot = lane&7, pre-swizzled global chunk = slot ^ (lane>>3)
    const int wrow = lane >> 3;
    const int wchk = (lane & 7) ^ wrow;
    const float* wg = w + (size_t)wrow * HDIM + k0 + wchk * 4;

    // A addressing (2 M-tiles of 16 tokens)
    const float* px0 = x + (size_t)(t0 + lr) * HDIM + k0 + lg * 8;
    const float* px1 = px0 + (size_t)16 * HDIM;

    f32x4 acc[2][4];
#pragma unroll
    for (int mt = 0; mt < 2; ++mt)
#pragma unroll
        for (int nt = 0; nt < 4; ++nt) {
            f32x4 z = {0.0f, 0.0f, 0.0f, 0.0f};
            acc[mt][nt] = z;
        }

    // prologue: W tile 0 -> LDS buf0; A tile 0 -> regs
#pragma unroll
    for (int p = 0; p < 8; ++p)
        load_lds16(wg + (size_t)(p * 8) * HDIM, Wbase + p * 256);

    float4 c00 = *(const float4*)(px0);
    float4 c01 = *(const float4*)(px0 + 4);
    float4 c10 = *(const float4*)(px1);
    float4 c11 = *(const float4*)(px1 + 4);

#pragma unroll 1
    for (int kk = 0; kk < 16; ++kk) {
        // split current A (consumes c-regs; compiler's wait on these also
        // guarantees the prologue/previous DMA count drains in order)
        bf16x8 Ah[2], Am[2], Al[2];
        split8(c00, c01, Ah[0], Am[0], Al[0]);
        split8(c10, c11, Ah[1], Am[1], Al[1]);

        // next k-chunk (wraps on last iter: wasted but valid loads keep the
        // vmcnt arithmetic uniform; loop-carried regs prevent DCE)
        const int kn = ((kk + 1) & 15) * 32;

        // A prefetch (register) + W DMA into the other buffer: 12 VMEM ops
        c00 = *(const float4*)(px0 + kn);
        c01 = *(const float4*)(px0 + kn + 4);
        c10 = *(const float4*)(px1 + kn);
        c11 = *(const float4*)(px1 + kn + 4);

        float* wd = Wbase + ((kk + 1) & 1) * 2048;
#pragma unroll
        for (int p = 0; p < 8; ++p)
            load_lds16(wg + (size_t)(p * 8) * HDIM + kn, wd + p * 256);

        // counted wait: allow this iter's 12 in flight, drain anything older
        // (i.e. the previous iter's 8 DMA -> current buffer is ready)
        asm volatile("s_waitcnt vmcnt(12)" ::: "memory");

        const float* Wc = Wbase + (kk & 1) * 2048;
#pragma unroll
        for (int nt = 0; nt < 4; ++nt) {
            const int e  = nt * 16 + lr;
            const int sw = lr & 7;                  // == e & 7
            const float* rb = Wc + e * 32;
            const float4 b0 = *(const float4*)(rb + (((2 * lg)     ^ sw) * 4));
            const float4 b1 = *(const float4*)(rb + (((2 * lg + 1) ^ sw) * 4));
            bf16x8 Bh, Bm, Bl;
            split8(b0, b1, Bh, Bm, Bl);
#pragma unroll
            for (int mt = 0; mt < 2; ++mt) {
                acc[mt][nt] = __builtin_amdgcn_mfma_f32_16x16x32_bf16(Ah[mt], Bh, acc[mt][nt], 0, 0, 0);
                acc[mt][nt] = __builtin_amdgcn_mfma_f32_16x16x32_bf16(Am[mt], Bh, acc[mt][nt], 0, 0, 0);
                acc[mt][nt] = __builtin_amdgcn_mfma_f32_16x16x32_bf16(Al[mt], Bh, acc[mt][nt], 0, 0, 0);
                acc[mt][nt] = __builtin_amdgcn_mfma_f32_16x16x32_bf16(Ah[mt], Bm, acc[mt][nt], 0, 0, 0);
                acc[mt][nt] = __builtin_amdgcn_mfma_f32_16x16x32_bf16(Am[mt], Bm, acc[mt][nt], 0, 0, 0);
                acc[mt][nt] = __builtin_amdgcn_mfma_f32_16x16x32_bf16(Ah[mt], Bl, acc[mt][nt], 0, 0, 0);
            }
        }
    }

    const float bv = bias[lane];

    // drain the wrapped final DMA (it targeted buf0 = the overlay region)
    asm volatile("s_waitcnt vmcnt(0)" ::: "memory");

    // overlay: partial logits for this wave's K-quarter into its own region
#pragma unroll
    for (int mt = 0; mt < 2; ++mt)
#pragma unroll
        for (int nt = 0; nt < 4; ++nt)
#pragma unroll
            for (int r = 0; r < 4; ++r)
                S[wv * 4096 + (mt * 16 + lg * 4 + r) * 64 + nt * 16 + lr] = acc[mt][nt][r];

    __syncthreads();

    // top-8 per token: wave wv handles tokens [wv*8, wv*8+8), lane = expert
#pragma unroll 1
    for (int i = 0; i < 8; ++i) {
        const int t = wv * 8 + i;
        const int o = t * 64 + lane;
        const float logit = S[o] + S[4096 + o] + S[8192 + o] + S[12288 + o];

        const float score = 1.0f / (1.0f + expf(-logit));
        float key = score + bv;

        float myscore = 0.0f;
        int   myidx   = 0;
        float denom   = 0.0f;

#pragma unroll
        for (int r = 0; r < 8; ++r) {
            float bk = key;
#pragma unroll
            for (int off = 32; off > 0; off >>= 1)
                bk = fmaxf(bk, __shfl_xor(bk, off));
            const unsigned long long msk = __ballot(key == bk);
            const int bi = __ffsll((long long)msk) - 1;   // lowest tied idx
            const float wsc = __shfl(score, bi);          // raw winner score
            denom += wsc;
            if (lane == r)  { myscore = wsc; myidx = bi; }
            if (lane == bi) key = -__builtin_inff();
        }

        const float factor = 2.5f / (denom + 1e-20f);
        if (lane < 8) {
            out_scores[(size_t)(t0 + t) * 8 + lane] = myscore * factor;
            out_idx  [(size_t)(t0 + t) * 8 + lane] = (float)myidx;
        }
    }
}

// ---------------------------------------------------------------------------
extern "C" void kernel_launch(void* const* d_in, const int* in_sizes, int n_in,
                              void* d_out, int out_size, void* d_ws, size_t ws_size,
                              hipStream_t stream)
{
    const float* x    = (const float*)d_in[0];   // [4,4096,2048] f32
    const float* bias = (const float*)d_in[1];   // [64] f32
    const float* w    = (const float*)d_in[2];   // [64,2048] f32

    float* out = (float*)d_out;

    router_fused<<<dim3(T_TOTAL / 32), dim3(256), 0, stream>>>(
        x, w, bias, out, out + (size_t)T_TOTAL * 8);
}